// Round 12
// baseline (188.324 us; speedup 1.0000x reference)
//
#include <hip/hip_runtime.h>
#include <stdint.h>

// GAT layer, B=4 N=2048 IN=128 F=64 H=4. adj int32; float tensors are
// bf16 OR fp32 (detected on-device, inline in kc/k1). Pipeline:
//  kc: dtype flag + convert W(+transpose),a1,a2 -> bf16; zero fp32 part accum
//  k1: MFMA g = h@W (h converted inline); store g_f in MFMA-B-FRAGMENT order;
//      sd/ss dots via LDS-redistributed fp32 sums (1 shuffle, not 192)
//  k2a: read adj once (int4 vec), row sums l -> E1, bitpack adj
//  k2b: fused softmax-numerators + att_mean + PV. QS=16 q-splits, 8192
//      single-wave blocks. EMPIRICAL LAWS:
//       - resident waves pinned ~6/CU at VGPR<=128, HALVES >128. KEEP <=128.
//       - only serial-path cuts move duration; memory-locality levers are
//         null-to-negative (R6: FETCH halved, time rose).
//       - g_f LAYOUT FRAGILE (R3 -22%); Bc/Bn roll FRAGILE (R5 -11%).
//      R0 FAILED: 4-wave lockstep 57->72. R1 WIN: deferred am stores ->52.9.
//      R2 FAILED: 2 p-tiles VGPR 160 ->63.2. R3/R4 FAILED: g_f relayout
//      ->64.6. R5 FAILED: alt-buffer refill ->58.7. R6 FAILED: XCD swizzle
//      ->60 (falsified fetch-latency theory). R7 WIN: setprio ->50.5.
//      R8 AMBIGUOUS (QS=8 profile artifact). R9 WIN: T14 prologue split +
//      no-barrier ->49.6. R10 WIN: exp(lrelu(x))=max(exp x, exp .2x) ->47.6.
//      R11: DELETE the LDS stage -- e2 values read from GLOBAL one stage
//      ahead into regs (same prefetch pattern as Bn; e2pn table is 768KB
//      L2-resident; quad-uniform 32B segments coalesce/broadcast). Removes
//      per-stage lgkm wait (~140cy x16) + all prologue staging + all LDS.
//      One vmcnt wait per stage covers both e2-cur and Bc (issued older).
//  k3: convert part accum -> h_prime

typedef unsigned char u8;
typedef unsigned short u16;
typedef unsigned int u32;
typedef unsigned long long u64;

typedef float f32x4 __attribute__((ext_vector_type(4)));
typedef short s16x8 __attribute__((ext_vector_type(8)));
typedef u32 u32x4 __attribute__((ext_vector_type(4)));

#define B_ 4
#define N_ 2048
#define IN_ 128
#define F_ 64
#define H_ 4
#define QS_ 16
#define PARTN_ (B_ * N_ * F_)

__device__ __forceinline__ float bf2f(u16 b) {
    u32 u = ((u32)b) << 16;
    return __builtin_bit_cast(float, u);
}
__device__ __forceinline__ u16 f2bf(float f) {
    u32 u = __builtin_bit_cast(u32, f);
    u += 0x7FFFu + ((u >> 16) & 1u);  // RNE
    return (u16)(u >> 16);
}
__device__ __forceinline__ u32 pk_bf16(float a, float b) {
#if defined(__has_builtin)
#if __has_builtin(__builtin_amdgcn_cvt_pk_bf16_f32)
    typedef __bf16 bf2_t __attribute__((ext_vector_type(2)));
    bf2_t p = __builtin_amdgcn_cvt_pk_bf16_f32(a, b);
    return __builtin_bit_cast(u32, p);
#else
    return (u32)f2bf(a) | (((u32)f2bf(b)) << 16);
#endif
#else
    return (u32)f2bf(a) | (((u32)f2bf(b)) << 16);
#endif
}

__device__ __forceinline__ u16 conv_elem(const void* p, int i, u32 isbf) {
    if (isbf) return ((const u16*)p)[i];
    return f2bf(((const float*)p)[i]);
}

// ---------------- kc: dtype detect + convert W/a1/a2 + zero part ----------------
__global__ __launch_bounds__(256) void kc_convert(
    const void* __restrict__ h, const void* __restrict__ W, const void* __restrict__ a1,
    const void* __restrict__ a2, u32* __restrict__ flag, u16* __restrict__ wt,
    u16* __restrict__ a1c, u16* __restrict__ a2c, float* __restrict__ partf) {
    __shared__ int cnt[4];
    __shared__ u32 isbf_s;
    int t = threadIdx.x;
    {  // dtype probe on first 256 words of h (identical result per block)
        u32 w = ((const u32*)h)[t];
        int e0 = (int)((w >> 7) & 0xFFu);
        int sane = (e0 >= 100 && e0 <= 145) ? 1 : 0;
#pragma unroll
        for (int m = 1; m < 64; m <<= 1) sane += __shfl_xor(sane, m, 64);
        if ((t & 63) == 0) cnt[t >> 6] = sane;
    }
    __syncthreads();
    if (t == 0) {
        int s = cnt[0] + cnt[1] + cnt[2] + cnt[3];
        isbf_s = (s >= 128) ? 1u : 0u;
        if (blockIdx.x == 0) *flag = isbf_s;
    }
    __syncthreads();
    u32 isbf = isbf_s;

    int j = blockIdx.x * 256 + t;
    if (j < IN_ * 256) {  // W: [128][256] row-major -> wt[c][k]
        int k = j >> 8, c = j & 255;
        wt[c * IN_ + k] = conv_elem(W, j, isbf);
        return;
    }
    j -= IN_ * 256;
    if (j < F_) {
        a1c[j] = conv_elem(a1, j, isbf);
        return;
    }
    j -= F_;
    if (j < F_) {
        a2c[j] = conv_elem(a2, j, isbf);
        return;
    }
    j -= F_;
    if (j < PARTN_) partf[j] = 0.f;
}

// g_f layout (u16), R1 ft-major order (empirically best; see header):
//   ((((b*H+h)*4 + ft)*64 + chunk)*64 + quad*16 + l15)*8 + j
//   holds g[f = ft*16+l15][q = chunk*32 + quad*8 + j]  (exact MFMA B-fragment)
__global__ __launch_bounds__(256) void k1_proj(
    const void* __restrict__ hraw, const u32* __restrict__ flag, const u16* __restrict__ Wt,
    const u16* __restrict__ a1, const u16* __restrict__ a2,
    u16* __restrict__ g_f, u16* __restrict__ sdb, u32* __restrict__ e2pn,
    float* __restrict__ ssA, float2* __restrict__ ssE) {
    int b = blockIdx.x >> 7;
    int n0 = (blockIdx.x & 127) * 16;
    int w = threadIdx.x >> 6;
    int lane = threadIdx.x & 63;
    int quad = lane >> 4, l15 = lane & 15;
    u32 isbf = *flag;

    f32x4 acc[4];
#pragma unroll
    for (int i = 0; i < 4; i++) acc[i] = 0.0f;

    s16x8 A[4];
    if (isbf) {
        const u16* hb = (const u16*)hraw;
#pragma unroll
        for (int kt = 0; kt < 4; kt++)
            A[kt] = *(const s16x8*)(hb + ((size_t)(b * N_ + n0 + l15) * IN_ + kt * 32 + quad * 8));
    } else {
        const float* hf = (const float*)hraw;
#pragma unroll
        for (int kt = 0; kt < 4; kt++) {
            size_t o = (size_t)(b * N_ + n0 + l15) * IN_ + kt * 32 + quad * 8;
            f32x4 lo = *(const f32x4*)(hf + o);
            f32x4 hi = *(const f32x4*)(hf + o + 4);
            u32* ap = (u32*)&A[kt];
            ap[0] = pk_bf16(lo[0], lo[1]);
            ap[1] = pk_bf16(lo[2], lo[3]);
            ap[2] = pk_bf16(hi[0], hi[1]);
            ap[3] = pk_bf16(hi[2], hi[3]);
        }
    }
#pragma unroll
    for (int kt = 0; kt < 4; kt++) {
#pragma unroll
        for (int ft = 0; ft < 4; ft++) {
            int c = w * 64 + ft * 16 + l15;
            const s16x8* bp = (const s16x8*)(Wt + ((size_t)c * IN_ + kt * 32 + quad * 8));
            acc[ft] = __builtin_amdgcn_mfma_f32_16x16x32_bf16(A[kt], *bp, acc[ft], 0, 0, 0);
        }
    }
    __shared__ float ct[4][64][20];  // [wave][f][n]
#pragma unroll
    for (int ft = 0; ft < 4; ft++)
#pragma unroll
        for (int r = 0; r < 4; r++) ct[w][ft * 16 + l15][quad * 4 + r] = acc[ft][r];
    __syncthreads();

    {  // fragment-order store: block covers quads {gq0, gq0+1} of chunk n0>>5
        int chunk = n0 >> 5;
        int gq0 = (n0 >> 3) & 2;
#pragma unroll
        for (int p = 0; p < 2; p++) {
            int ft = p * 2 + (lane >> 5);
            int lq = (lane >> 4) & 1;
            int fl = lane & 15;
            s16x8 tv;
#pragma unroll
            for (int j = 0; j < 8; j++) tv[j] = (short)f2bf(ct[w][ft * 16 + fl][lq * 8 + j]);
            size_t off =
                ((size_t)(((b * H_ + w) * 4 + ft) * 64 + chunk) * 64 + (gq0 + lq) * 16 + fl) * 8;
            *(s16x8*)(g_f + off) = tv;
        }
    }
    // sd/ss dots: lane -> (n = lane&15, vec = (lane>>4)&1, half = lane>>5)
    {
        int dn = lane & 15;
        int dvec = (lane >> 4) & 1;
        int dhalf = lane >> 5;
        const u16* av = dvec ? a2 : a1;
        float x = 0.f;
#pragma unroll
        for (int i = 0; i < 32; i++) {
            int f = dhalf * 32 + i;
            x += ct[w][f][dn] * bf2f(av[f]);
        }
        x += __shfl_xor(x, 32, 64);
        if (lane < 32) {
            size_t o = (size_t)(b * H_ + w) * N_ + n0 + dn;
            if (dvec == 0) {
                sdb[o] = f2bf(x);
                float e2p = __expf(x), e2n = __expf(0.2f * x);
                e2pn[o] = (((u32)f2bf(e2p)) << 16) | (u32)f2bf(e2n);
            } else {
                ssA[o] = x;
                ssE[o] = make_float2(__expf(x), __expf(0.2f * x));
            }
        }
    }
}

// ---------------- k2a: denominators + adj bitpack (vectorized, no ballots) ---
__global__ __launch_bounds__(256) void k2a_rowsum(
    const int* __restrict__ adj, const u16* __restrict__ sdb, const u32* __restrict__ e2pn,
    const float* __restrict__ ssA, const float2* __restrict__ ssE,
    float2* __restrict__ E1, u32* __restrict__ pk32) {
    int b = blockIdx.x >> 9;
    int p0 = (blockIdx.x & 511) * 4;
    int t = threadIdx.x;
    int w = t >> 6, lane = t & 63;

    __shared__ u8 nib[4][512];

    float tau[4][4];
#pragma unroll
    for (int r = 0; r < 4; r++)
#pragma unroll
        for (int hh = 0; hh < 4; hh++)
            tau[r][hh] = -ssA[(size_t)(b * H_ + hh) * N_ + p0 + r];

    float S[32];  // [(r*4+h)*2 + {p,n}]
#pragma unroll
    for (int i = 0; i < 32; i++) S[i] = 0.f;

#pragma unroll
    for (int i = 0; i < 2; i++) {
        int qi = i * 256 + t;
        int q = qi * 4;
        float af[4][4];
#pragma unroll
        for (int r = 0; r < 4; r++) {
            int4 av = *(const int4*)(adj + (size_t)(b * N_ + p0 + r) * N_ + q);
            af[r][0] = (av.x != 0) ? 1.f : 0.f;
            af[r][1] = (av.y != 0) ? 1.f : 0.f;
            af[r][2] = (av.z != 0) ? 1.f : 0.f;
            af[r][3] = (av.w != 0) ? 1.f : 0.f;
            u32 nb = (av.x != 0 ? 1u : 0u) | (av.y != 0 ? 2u : 0u) |
                     (av.z != 0 ? 4u : 0u) | (av.w != 0 ? 8u : 0u);
            nib[r][qi] = (u8)nb;
        }
#pragma unroll
        for (int hh = 0; hh < 4; hh++) {
            size_t o = (size_t)(b * H_ + hh) * N_ + q;
            u64 sd4 = *(const u64*)(sdb + o);
            u32x4 pn4 = *(const u32x4*)(e2pn + o);
            float sdf[4], e2p[4], e2n[4];
#pragma unroll
            for (int j = 0; j < 4; j++) {
                sdf[j] = bf2f((u16)(sd4 >> (16 * j)));
                e2p[j] = __builtin_bit_cast(float, pn4[j] & 0xFFFF0000u);
                e2n[j] = __builtin_bit_cast(float, pn4[j] << 16);
            }
#pragma unroll
            for (int r = 0; r < 4; r++) {
#pragma unroll
                for (int j = 0; j < 4; j++) {
                    bool ge = sdf[j] >= tau[r][hh];
                    S[(r * 4 + hh) * 2 + 0] += ge ? af[r][j] * e2p[j] : 0.f;
                    S[(r * 4 + hh) * 2 + 1] += ge ? 0.f : af[r][j] * e2n[j];
                }
            }
        }
    }
    __syncthreads();
    {
        int r = t >> 6, m8 = t & 63;
        u64 nn = *(const u64*)&nib[r][m8 * 8];
        u32 wd = 0;
#pragma unroll
        for (int d = 0; d < 4; d++) {
            u32 lo = (u32)(nn >> (16 * d)) & 0xFu;
            u32 hi = (u32)(nn >> (16 * d + 8)) & 0xFu;
            wd |= (lo | (hi << 4)) << (8 * d);
        }
        pk32[(size_t)(b * N_ + p0 + r) * 64 + m8] = wd;
    }
#pragma unroll
    for (int k = 0; k < 32; k++) {
        float x = S[k];
#pragma unroll
        for (int m = 1; m < 64; m <<= 1) x += __shfl_xor(x, m, 64);
        S[k] = x;
    }
    __shared__ float sred[4][32];
    if (lane == 0) {
#pragma unroll
        for (int k = 0; k < 32; k++) sred[w][k] = S[k];
    }
    __syncthreads();
    if (t < 16) {
        int r = t >> 2, hh = t & 3;
        float sp = 0.f, sn = 0.f;
#pragma unroll
        for (int ww = 0; ww < 4; ww++) {
            sp += sred[ww][t * 2];
            sn += sred[ww][t * 2 + 1];
        }
        size_t o = (size_t)(b * H_ + hh) * N_ + p0 + r;
        float2 se = ssE[o];
        float l = se.x * sp + se.y * sn;
        float inv = (l > 0.f) ? 0.25f / l : 0.f;  // fold 1/H and 1/l
        E1[o] = make_float2(se.x * inv, se.y * inv);
    }
}

// ---------------- k2b: fused attention + att_mean + PV ----------------
// grid = B * 128 ptiles * 16 qsplits = 8192 single-wave blocks (128 q each).
// R11: NO LDS. e2 values read from global one stage ahead into registers
// (E2na/E2nb), same prefetch pattern as Bn; consumed next stage from
// E2ca/E2cb. One vmcnt wait per stage covers e2-cur AND Bc (issued older).
// R10: w = bit * max(E1p*exp(sd), E1n*exp(0.2 sd)).
// R7: setprio around MFMA cluster. R1: am accumulated in regs, stored once
// at the end (vmcnt retires in order; scattered mid-loop stores block
// later prefetches).
__global__ __launch_bounds__(64) void k2b_attn(
    const u16* __restrict__ sdb, const u32* __restrict__ e2pn, const float* __restrict__ ssA,
    const float2* __restrict__ E1, const u32* __restrict__ pk32,
    const u16* __restrict__ g_f, const u32* __restrict__ flag, void* __restrict__ d_out_v,
    float* __restrict__ partf) {
    int bid = blockIdx.x;
    int s = bid & (QS_ - 1);
    int pt = (bid >> 4) & 127;
    int b = bid >> 11;
    int qb = s * (N_ / QS_);  // 128 q per block
    int lane = threadIdx.x;   // 0..63
    int quad = lane >> 4, l15 = lane & 15;
    int p0 = pt * 16;
    int row = p0 + l15;
    u32 isbf = *flag;

    // per-lane e2 base: stage (c,hh) reads 8 u32 at eb + hh*N_ + c*32 + quad*8
    const u32* eb = e2pn + (size_t)(b * H_) * N_ + qb + quad * 8;

    float E1p[4], E1n[4];
#pragma unroll
    for (int hh = 0; hh < 4; hh++) {
        size_t o = (size_t)(b * H_ + hh) * N_ + row;
        float2 e1 = E1[o];
        E1p[hh] = e1.x;
        E1n[hh] = e1.y;
    }
    const u32* pkrow = pk32 + (size_t)(b * N_ + row) * 64 + (qb >> 5);
    u32 pkw[4];
    *(u32x4*)&pkw[0] = *(const u32x4*)pkrow;

    const size_t hstride = (size_t)4 * 64 * 512;  // per-head span in u16
    const u16* gb = g_f + (size_t)b * H_ * hstride + (size_t)(qb >> 5) * 512 + lane * 8;

    s16x8 Bc[4], Bn[4];
#pragma unroll
    for (int ft = 0; ft < 4; ft++) Bc[ft] = *(const s16x8*)(gb + (size_t)ft * 32768);

    // e2 regs for current stage (stage 0 = c0,hh0)
    u32x4 E2ca = *(const u32x4*)(eb + 0);
    u32x4 E2cb = *(const u32x4*)(eb + 4);
    u32x4 E2na, E2nb;

    f32x4 acc[4];  // shared across heads (h' sums over heads)
#pragma unroll
    for (int i = 0; i < 4; i++) acc[i] = 0.0f;

    size_t am_base = ((size_t)(b * N_ + row)) * N_ + qb + quad * 8;
    u16* amb = (u16*)d_out_v + (size_t)B_ * N_ * F_;
    float* amf = (float*)d_out_v + (size_t)B_ * N_ * F_;

    float amv[4][8];  // att_mean accum, per c; static indices only (full unroll)
#pragma unroll
    for (int c = 0; c < 4; c++)
#pragma unroll
        for (int j = 0; j < 8; j++) amv[c][j] = 0.f;

#pragma unroll
    for (int c = 0; c < 4; c++) {
        u32 byte_ = (pkw[c] >> (quad * 8)) & 0xFFu;

#pragma unroll
        for (int hh = 0; hh < 4; hh++) {
            int idx = (c * 4 + hh + 1) & 15;  // next stage (wraps harmlessly)
            int c2 = idx >> 2, h2 = idx & 3;
            {  // prefetch next stage's B fragments
#pragma unroll
                for (int ft = 0; ft < 4; ft++)
                    Bn[ft] = *(const s16x8*)(gb + (size_t)h2 * hstride + (size_t)ft * 32768 +
                                             (size_t)c2 * 512);
            }
            {  // prefetch next stage's e2 values (global, L2-resident)
                const u32* ep_ = eb + (size_t)h2 * N_ + c2 * 32;
                E2na = *(const u32x4*)(ep_ + 0);
                E2nb = *(const u32x4*)(ep_ + 4);
            }
            float wv[8];
#pragma unroll
            for (int j = 0; j < 8; j++) {
                u32 pn = (j < 4) ? E2ca[j] : E2cb[j - 4];
                float ep = __builtin_bit_cast(float, pn & 0xFFFF0000u);
                float en = __builtin_bit_cast(float, pn << 16);
                float ww = fmaxf(E1p[hh] * ep, E1n[hh] * en);
                ww = ((byte_ >> j) & 1u) ? ww : 0.f;
                wv[j] = ww;
                amv[c][j] += ww;
            }
            s16x8 af;
            u32* afp = (u32*)&af;
#pragma unroll
            for (int j = 0; j < 4; j++) afp[j] = pk_bf16(wv[2 * j], wv[2 * j + 1]);
            __builtin_amdgcn_s_setprio(1);  // R7: favor this wave's MFMA burst
#pragma unroll
            for (int ft = 0; ft < 4; ft++)
                acc[ft] = __builtin_amdgcn_mfma_f32_16x16x32_bf16(af, Bc[ft], acc[ft], 0, 0, 0);
            __builtin_amdgcn_s_setprio(0);
#pragma unroll
            for (int ft = 0; ft < 4; ft++) Bc[ft] = Bn[ft];
            E2ca = E2na;
            E2cb = E2nb;
        }
    }
    // ---- deferred att_mean stores (after all loads/MFMA; nothing waits on these)
    if (isbf) {
#pragma unroll
        for (int c = 0; c < 4; c++) {
            s16x8 amp;
            u32* ampp = (u32*)&amp;
#pragma unroll
            for (int j = 0; j < 4; j++) ampp[j] = pk_bf16(amv[c][2 * j], amv[c][2 * j + 1]);
            *(s16x8*)(amb + am_base + c * 32) = amp;
        }
    } else {
#pragma unroll
        for (int c = 0; c < 4; c++) {
            f32x4 lo, hi;
#pragma unroll
            for (int j = 0; j < 4; j++) { lo[j] = amv[c][j]; hi[j] = amv[c][j + 4]; }
            *(f32x4*)(amf + am_base + c * 32) = lo;
            *(f32x4*)(amf + am_base + c * 32 + 4) = hi;
        }
    }
#pragma unroll
    for (int ft = 0; ft < 4; ft++) {
#pragma unroll
        for (int r = 0; r < 4; r++) {
            int pout = p0 + quad * 4 + r;
            int f = ft * 16 + l15;
            atomicAdd(&partf[(size_t)(b * N_ + pout) * F_ + f], acc[ft][r]);
        }
    }
}

__global__ __launch_bounds__(256) void k3_reduce(const float* __restrict__ partf,
                                                 const u32* __restrict__ flag,
                                                 void* __restrict__ out) {
    int idx = blockIdx.x * 256 + threadIdx.x;
    float s = partf[idx];
    if (*flag)
        ((u16*)out)[idx] = f2bf(s);
    else
        ((float*)out)[idx] = s;
}

extern "C" void kernel_launch(void* const* d_in, const int* in_sizes, int n_in,
                              void* d_out, int out_size, void* d_ws, size_t ws_size,
                              hipStream_t stream) {
    const void* h = d_in[0];
    const int* adj = (const int*)d_in[1];
    const void* W = d_in[2];
    const void* a1 = d_in[3];
    const void* a2 = d_in[4];

    char* ws = (char*)d_ws;
    u32* flag = (u32*)(ws + 0);
    u16* a1c = (u16*)(ws + 64);
    u16* a2c = (u16*)(ws + 192);
    u16* wt = (u16*)(ws + 1024);           //  64 KB, ends 66560
    u16* g_f = (u16*)(ws + 66560);         //   4 MB, ends 4260864
    u16* sdb = (u16*)(ws + 4260864);       //  64 KB, ends 4326400
    u32* e2pn = (u32*)(ws + 4326400);      // 128 KB, ends 4457472
    float* ssA = (float*)(ws + 4457472);   // 128 KB, ends 4588544
    float2* ssE = (float2*)(ws + 4588544); // 256 KB, ends 4850688
    float2* E1 = (float2*)(ws + 4850688);  // 256 KB, ends 5112832
    u32* pk = (u32*)(ws + 5112832);        //   2 MB, ends 7209984
    float* partf = (float*)(ws + 7209984); //   2 MB, ends 9307136 (~9.3 MB)

    const int KC_TOT = IN_ * 256 + 2 * F_ + PARTN_;
    kc_convert<<<(KC_TOT + 255) / 256, 256, 0, stream>>>(h, W, a1, a2, flag, wt, a1c, a2c,
                                                         partf);
    k1_proj<<<512, 256, 0, stream>>>(h, flag, wt, a1c, a2c, g_f, sdb, e2pn, ssA, ssE);
    k2a_rowsum<<<2048, 256, 0, stream>>>(adj, sdb, e2pn, ssA, ssE, E1, pk);
    k2b_attn<<<8192, 64, 0, stream>>>(sdb, e2pn, ssA, E1, (const u32*)pk, g_f, flag,
                                      d_out, partf);
    k3_reduce<<<2048, 256, 0, stream>>>(partf, flag, d_out);
}

// Round 13
// 182.826 us; speedup vs baseline: 1.0301x; 1.0301x over previous
//
#include <hip/hip_runtime.h>
#include <stdint.h>

// GAT layer, B=4 N=2048 IN=128 F=64 H=4. adj int32; float tensors are
// bf16 OR fp32 (detected on-device, inline in kc/k1). Pipeline:
//  kc: dtype flag + convert W(+transpose),a1,a2 -> bf16; zero fp32 part accum
//  k1: MFMA g = h@W (h converted inline); store g_f in MFMA-B-FRAGMENT order;
//      sd/ss dots via LDS-redistributed fp32 sums (1 shuffle, not 192)
//  k2a: read adj once (int4 vec), row sums l -> E1, bitpack adj
//  k2b: fused softmax-numerators + att_mean + PV. QS=16 q-splits, 8192
//      single-wave blocks. EMPIRICAL LAWS:
//       - resident waves pinned ~6/CU at VGPR<=128, HALVES >128. KEEP <=128.
//       - only serial-path cuts move duration; memory-locality levers are
//         null-to-negative (R6: FETCH halved, time rose).
//       - g_f LAYOUT FRAGILE (R3 -22%); Bc/Bn roll FRAGILE (R5 -11%).
//       - TWO-COUNTER LAW (R11): softmax inputs MUST stay in the lgkm
//         domain (LDS), B-fragments in vmcnt. R11 moved e2 to global
//         prefetch -> e2 became newest vmcnt entry; its wait retired the
//         older Bn prefetches too (in-order) -> per-stage vmcnt(0) drain,
//         47.6->70.7. The LDS stage is not overhead; it is the decoupler.
//      R0 FAILED: 4-wave lockstep 57->72. R1 WIN: deferred am stores ->52.9.
//      R2 FAILED: 2 p-tiles VGPR 160 ->63.2. R3/R4 FAILED: g_f relayout
//      ->64.6. R5 FAILED: alt-buffer refill ->58.7. R6 FAILED: XCD swizzle
//      ->60. R7 WIN: setprio ->50.5. R8 AMBIGUOUS (profile artifact).
//      R9 WIN: T14 prologue split + no-barrier ->49.6. R10 WIN:
//      exp(lrelu(x))=max(exp x, exp .2x) ->47.6. R11 FAILED: global e2
//      prefetch ->70.7 (two-counter law). R12: exact revert to R10.
//  k3: convert part accum -> h_prime

typedef unsigned char u8;
typedef unsigned short u16;
typedef unsigned int u32;
typedef unsigned long long u64;

typedef float f32x4 __attribute__((ext_vector_type(4)));
typedef short s16x8 __attribute__((ext_vector_type(8)));
typedef u32 u32x4 __attribute__((ext_vector_type(4)));

#define B_ 4
#define N_ 2048
#define IN_ 128
#define F_ 64
#define H_ 4
#define QS_ 16
#define PARTN_ (B_ * N_ * F_)

__device__ __forceinline__ float bf2f(u16 b) {
    u32 u = ((u32)b) << 16;
    return __builtin_bit_cast(float, u);
}
__device__ __forceinline__ u16 f2bf(float f) {
    u32 u = __builtin_bit_cast(u32, f);
    u += 0x7FFFu + ((u >> 16) & 1u);  // RNE
    return (u16)(u >> 16);
}
__device__ __forceinline__ u32 pk_bf16(float a, float b) {
#if defined(__has_builtin)
#if __has_builtin(__builtin_amdgcn_cvt_pk_bf16_f32)
    typedef __bf16 bf2_t __attribute__((ext_vector_type(2)));
    bf2_t p = __builtin_amdgcn_cvt_pk_bf16_f32(a, b);
    return __builtin_bit_cast(u32, p);
#else
    return (u32)f2bf(a) | (((u32)f2bf(b)) << 16);
#endif
#else
    return (u32)f2bf(a) | (((u32)f2bf(b)) << 16);
#endif
}

__device__ __forceinline__ u16 conv_elem(const void* p, int i, u32 isbf) {
    if (isbf) return ((const u16*)p)[i];
    return f2bf(((const float*)p)[i]);
}

// ---------------- kc: dtype detect + convert W/a1/a2 + zero part ----------------
__global__ __launch_bounds__(256) void kc_convert(
    const void* __restrict__ h, const void* __restrict__ W, const void* __restrict__ a1,
    const void* __restrict__ a2, u32* __restrict__ flag, u16* __restrict__ wt,
    u16* __restrict__ a1c, u16* __restrict__ a2c, float* __restrict__ partf) {
    __shared__ int cnt[4];
    __shared__ u32 isbf_s;
    int t = threadIdx.x;
    {  // dtype probe on first 256 words of h (identical result per block)
        u32 w = ((const u32*)h)[t];
        int e0 = (int)((w >> 7) & 0xFFu);
        int sane = (e0 >= 100 && e0 <= 145) ? 1 : 0;
#pragma unroll
        for (int m = 1; m < 64; m <<= 1) sane += __shfl_xor(sane, m, 64);
        if ((t & 63) == 0) cnt[t >> 6] = sane;
    }
    __syncthreads();
    if (t == 0) {
        int s = cnt[0] + cnt[1] + cnt[2] + cnt[3];
        isbf_s = (s >= 128) ? 1u : 0u;
        if (blockIdx.x == 0) *flag = isbf_s;
    }
    __syncthreads();
    u32 isbf = isbf_s;

    int j = blockIdx.x * 256 + t;
    if (j < IN_ * 256) {  // W: [128][256] row-major -> wt[c][k]
        int k = j >> 8, c = j & 255;
        wt[c * IN_ + k] = conv_elem(W, j, isbf);
        return;
    }
    j -= IN_ * 256;
    if (j < F_) {
        a1c[j] = conv_elem(a1, j, isbf);
        return;
    }
    j -= F_;
    if (j < F_) {
        a2c[j] = conv_elem(a2, j, isbf);
        return;
    }
    j -= F_;
    if (j < PARTN_) partf[j] = 0.f;
}

// g_f layout (u16), R1 ft-major order (empirically best; see header):
//   ((((b*H+h)*4 + ft)*64 + chunk)*64 + quad*16 + l15)*8 + j
//   holds g[f = ft*16+l15][q = chunk*32 + quad*8 + j]  (exact MFMA B-fragment)
__global__ __launch_bounds__(256) void k1_proj(
    const void* __restrict__ hraw, const u32* __restrict__ flag, const u16* __restrict__ Wt,
    const u16* __restrict__ a1, const u16* __restrict__ a2,
    u16* __restrict__ g_f, u16* __restrict__ sdb, u32* __restrict__ e2pn,
    float* __restrict__ ssA, float2* __restrict__ ssE) {
    int b = blockIdx.x >> 7;
    int n0 = (blockIdx.x & 127) * 16;
    int w = threadIdx.x >> 6;
    int lane = threadIdx.x & 63;
    int quad = lane >> 4, l15 = lane & 15;
    u32 isbf = *flag;

    f32x4 acc[4];
#pragma unroll
    for (int i = 0; i < 4; i++) acc[i] = 0.0f;

    s16x8 A[4];
    if (isbf) {
        const u16* hb = (const u16*)hraw;
#pragma unroll
        for (int kt = 0; kt < 4; kt++)
            A[kt] = *(const s16x8*)(hb + ((size_t)(b * N_ + n0 + l15) * IN_ + kt * 32 + quad * 8));
    } else {
        const float* hf = (const float*)hraw;
#pragma unroll
        for (int kt = 0; kt < 4; kt++) {
            size_t o = (size_t)(b * N_ + n0 + l15) * IN_ + kt * 32 + quad * 8;
            f32x4 lo = *(const f32x4*)(hf + o);
            f32x4 hi = *(const f32x4*)(hf + o + 4);
            u32* ap = (u32*)&A[kt];
            ap[0] = pk_bf16(lo[0], lo[1]);
            ap[1] = pk_bf16(lo[2], lo[3]);
            ap[2] = pk_bf16(hi[0], hi[1]);
            ap[3] = pk_bf16(hi[2], hi[3]);
        }
    }
#pragma unroll
    for (int kt = 0; kt < 4; kt++) {
#pragma unroll
        for (int ft = 0; ft < 4; ft++) {
            int c = w * 64 + ft * 16 + l15;
            const s16x8* bp = (const s16x8*)(Wt + ((size_t)c * IN_ + kt * 32 + quad * 8));
            acc[ft] = __builtin_amdgcn_mfma_f32_16x16x32_bf16(A[kt], *bp, acc[ft], 0, 0, 0);
        }
    }
    __shared__ float ct[4][64][20];  // [wave][f][n]
#pragma unroll
    for (int ft = 0; ft < 4; ft++)
#pragma unroll
        for (int r = 0; r < 4; r++) ct[w][ft * 16 + l15][quad * 4 + r] = acc[ft][r];
    __syncthreads();

    {  // fragment-order store: block covers quads {gq0, gq0+1} of chunk n0>>5
        int chunk = n0 >> 5;
        int gq0 = (n0 >> 3) & 2;
#pragma unroll
        for (int p = 0; p < 2; p++) {
            int ft = p * 2 + (lane >> 5);
            int lq = (lane >> 4) & 1;
            int fl = lane & 15;
            s16x8 tv;
#pragma unroll
            for (int j = 0; j < 8; j++) tv[j] = (short)f2bf(ct[w][ft * 16 + fl][lq * 8 + j]);
            size_t off =
                ((size_t)(((b * H_ + w) * 4 + ft) * 64 + chunk) * 64 + (gq0 + lq) * 16 + fl) * 8;
            *(s16x8*)(g_f + off) = tv;
        }
    }
    // sd/ss dots: lane -> (n = lane&15, vec = (lane>>4)&1, half = lane>>5)
    {
        int dn = lane & 15;
        int dvec = (lane >> 4) & 1;
        int dhalf = lane >> 5;
        const u16* av = dvec ? a2 : a1;
        float x = 0.f;
#pragma unroll
        for (int i = 0; i < 32; i++) {
            int f = dhalf * 32 + i;
            x += ct[w][f][dn] * bf2f(av[f]);
        }
        x += __shfl_xor(x, 32, 64);
        if (lane < 32) {
            size_t o = (size_t)(b * H_ + w) * N_ + n0 + dn;
            if (dvec == 0) {
                sdb[o] = f2bf(x);
                float e2p = __expf(x), e2n = __expf(0.2f * x);
                e2pn[o] = (((u32)f2bf(e2p)) << 16) | (u32)f2bf(e2n);
            } else {
                ssA[o] = x;
                ssE[o] = make_float2(__expf(x), __expf(0.2f * x));
            }
        }
    }
}

// ---------------- k2a: denominators + adj bitpack (vectorized, no ballots) ---
__global__ __launch_bounds__(256) void k2a_rowsum(
    const int* __restrict__ adj, const u16* __restrict__ sdb, const u32* __restrict__ e2pn,
    const float* __restrict__ ssA, const float2* __restrict__ ssE,
    float2* __restrict__ E1, u32* __restrict__ pk32) {
    int b = blockIdx.x >> 9;
    int p0 = (blockIdx.x & 511) * 4;
    int t = threadIdx.x;
    int w = t >> 6, lane = t & 63;

    __shared__ u8 nib[4][512];

    float tau[4][4];
#pragma unroll
    for (int r = 0; r < 4; r++)
#pragma unroll
        for (int hh = 0; hh < 4; hh++)
            tau[r][hh] = -ssA[(size_t)(b * H_ + hh) * N_ + p0 + r];

    float S[32];  // [(r*4+h)*2 + {p,n}]
#pragma unroll
    for (int i = 0; i < 32; i++) S[i] = 0.f;

#pragma unroll
    for (int i = 0; i < 2; i++) {
        int qi = i * 256 + t;
        int q = qi * 4;
        float af[4][4];
#pragma unroll
        for (int r = 0; r < 4; r++) {
            int4 av = *(const int4*)(adj + (size_t)(b * N_ + p0 + r) * N_ + q);
            af[r][0] = (av.x != 0) ? 1.f : 0.f;
            af[r][1] = (av.y != 0) ? 1.f : 0.f;
            af[r][2] = (av.z != 0) ? 1.f : 0.f;
            af[r][3] = (av.w != 0) ? 1.f : 0.f;
            u32 nb = (av.x != 0 ? 1u : 0u) | (av.y != 0 ? 2u : 0u) |
                     (av.z != 0 ? 4u : 0u) | (av.w != 0 ? 8u : 0u);
            nib[r][qi] = (u8)nb;
        }
#pragma unroll
        for (int hh = 0; hh < 4; hh++) {
            size_t o = (size_t)(b * H_ + hh) * N_ + q;
            u64 sd4 = *(const u64*)(sdb + o);
            u32x4 pn4 = *(const u32x4*)(e2pn + o);
            float sdf[4], e2p[4], e2n[4];
#pragma unroll
            for (int j = 0; j < 4; j++) {
                sdf[j] = bf2f((u16)(sd4 >> (16 * j)));
                e2p[j] = __builtin_bit_cast(float, pn4[j] & 0xFFFF0000u);
                e2n[j] = __builtin_bit_cast(float, pn4[j] << 16);
            }
#pragma unroll
            for (int r = 0; r < 4; r++) {
#pragma unroll
                for (int j = 0; j < 4; j++) {
                    bool ge = sdf[j] >= tau[r][hh];
                    S[(r * 4 + hh) * 2 + 0] += ge ? af[r][j] * e2p[j] : 0.f;
                    S[(r * 4 + hh) * 2 + 1] += ge ? 0.f : af[r][j] * e2n[j];
                }
            }
        }
    }
    __syncthreads();
    {
        int r = t >> 6, m8 = t & 63;
        u64 nn = *(const u64*)&nib[r][m8 * 8];
        u32 wd = 0;
#pragma unroll
        for (int d = 0; d < 4; d++) {
            u32 lo = (u32)(nn >> (16 * d)) & 0xFu;
            u32 hi = (u32)(nn >> (16 * d + 8)) & 0xFu;
            wd |= (lo | (hi << 4)) << (8 * d);
        }
        pk32[(size_t)(b * N_ + p0 + r) * 64 + m8] = wd;
    }
#pragma unroll
    for (int k = 0; k < 32; k++) {
        float x = S[k];
#pragma unroll
        for (int m = 1; m < 64; m <<= 1) x += __shfl_xor(x, m, 64);
        S[k] = x;
    }
    __shared__ float sred[4][32];
    if (lane == 0) {
#pragma unroll
        for (int k = 0; k < 32; k++) sred[w][k] = S[k];
    }
    __syncthreads();
    if (t < 16) {
        int r = t >> 2, hh = t & 3;
        float sp = 0.f, sn = 0.f;
#pragma unroll
        for (int ww = 0; ww < 4; ww++) {
            sp += sred[ww][t * 2];
            sn += sred[ww][t * 2 + 1];
        }
        size_t o = (size_t)(b * H_ + hh) * N_ + p0 + r;
        float2 se = ssE[o];
        float l = se.x * sp + se.y * sn;
        float inv = (l > 0.f) ? 0.25f / l : 0.f;  // fold 1/H and 1/l
        E1[o] = make_float2(se.x * inv, se.y * inv);
    }
}

// ---------------- k2b: fused attention + att_mean + PV ----------------
// grid = B * 128 ptiles * 16 qsplits = 8192 single-wave blocks (128 q each).
// R10: w = bit * max(E1p*exp(sd), E1n*exp(0.2 sd)) -- exp(lrelu(x)) =
// max(exp(x), exp(0.2x)) since lrelu(x)=max(x,0.2x) and exp is monotone;
// the nonneg scales commute with max. No sd compare, no tau, no lsd.
// R9: T14 prologue split (staging loads issued first, LDS writes late),
// no __syncthreads (single-wave block; lgkmcnt orders ds_write->ds_read).
// R7: setprio around MFMA cluster. R1: am accumulated in regs, stored once
// at the end. TWO-COUNTER LAW (R11): le2 stays in LDS/lgkm; B-fragments in
// vmcnt -- the two wait queues pipeline against each other.
__global__ __launch_bounds__(64) void k2b_attn(
    const u16* __restrict__ sdb, const u32* __restrict__ e2pn, const float* __restrict__ ssA,
    const float2* __restrict__ E1, const u32* __restrict__ pk32,
    const u16* __restrict__ g_f, const u32* __restrict__ flag, void* __restrict__ d_out_v,
    float* __restrict__ partf) {
    int bid = blockIdx.x;
    int s = bid & (QS_ - 1);
    int pt = (bid >> 4) & 127;
    int b = bid >> 11;
    int qb = s * (N_ / QS_);  // 128 q per block
    int lane = threadIdx.x;   // 0..63
    int quad = lane >> 4, l15 = lane & 15;
    int p0 = pt * 16;
    int row = p0 + l15;
    u32 isbf = *flag;

    __shared__ __align__(8) u32 le2[4][128];

    // ---- T14 issue-early: staging loads first (oldest -> retire first)
    u64 t_e2[4];
#pragma unroll
    for (int hh = 0; hh < 4; hh++) {
        size_t o = (size_t)(b * H_ + hh) * N_ + qb + lane * 2;
        t_e2[hh] = *(const u64*)(e2pn + o);
    }

    // ---- newer loads issued while staging loads are in flight
    float E1p[4], E1n[4];
#pragma unroll
    for (int hh = 0; hh < 4; hh++) {
        size_t o = (size_t)(b * H_ + hh) * N_ + row;
        float2 e1 = E1[o];
        E1p[hh] = e1.x;
        E1n[hh] = e1.y;
    }
    const u32* pkrow = pk32 + (size_t)(b * N_ + row) * 64 + (qb >> 5);
    u32 pkw[4];
#pragma unroll
    for (int c = 0; c < 4; c++) pkw[c] = pkrow[c];

    const size_t hstride = (size_t)4 * 64 * 512;  // per-head span in u16
    const u16* gb = g_f + (size_t)b * H_ * hstride + (size_t)(qb >> 5) * 512 + lane * 8;

    s16x8 Bc[4], Bn[4];
#pragma unroll
    for (int ft = 0; ft < 4; ft++) Bc[ft] = *(const s16x8*)(gb + (size_t)ft * 32768);

    // ---- write-late: LDS staging (waits only the oldest loads; Bc stays
    // in flight). Single-wave block: no barrier needed, lgkmcnt orders
    // ds_write -> ds_read.
#pragma unroll
    for (int hh = 0; hh < 4; hh++) {
        *(u64*)&le2[hh][lane * 2] = t_e2[hh];
    }

    f32x4 acc[4];  // shared across heads (h' sums over heads)
#pragma unroll
    for (int i = 0; i < 4; i++) acc[i] = 0.0f;

    size_t am_base = ((size_t)(b * N_ + row)) * N_ + qb + quad * 8;
    u16* amb = (u16*)d_out_v + (size_t)B_ * N_ * F_;
    float* amf = (float*)d_out_v + (size_t)B_ * N_ * F_;

    float amv[4][8];  // att_mean accum, per c; static indices only (full unroll)
#pragma unroll
    for (int c = 0; c < 4; c++)
#pragma unroll
        for (int j = 0; j < 8; j++) amv[c][j] = 0.f;

#pragma unroll
    for (int c = 0; c < 4; c++) {
        int qq = c * 32 + quad * 8;
        u32 byte_ = (pkw[c] >> (quad * 8)) & 0xFFu;

#pragma unroll
        for (int hh = 0; hh < 4; hh++) {
            {  // prefetch next (c,hh) stage's B fragments
                int idx = (c * 4 + hh + 1) & 15;
                int c2 = idx >> 2, h2 = idx & 3;
#pragma unroll
                for (int ft = 0; ft < 4; ft++)
                    Bn[ft] = *(const s16x8*)(gb + (size_t)h2 * hstride + (size_t)ft * 32768 +
                                             (size_t)c2 * 512);
            }
            u32x4 e2a = *(const u32x4*)&le2[hh][qq];
            u32x4 e2b = *(const u32x4*)&le2[hh][qq + 4];
            float wv[8];
#pragma unroll
            for (int j = 0; j < 8; j++) {
                u32 pn = (j < 4) ? e2a[j] : e2b[j - 4];
                float ep = __builtin_bit_cast(float, pn & 0xFFFF0000u);
                float en = __builtin_bit_cast(float, pn << 16);
                float ww = fmaxf(E1p[hh] * ep, E1n[hh] * en);
                ww = ((byte_ >> j) & 1u) ? ww : 0.f;
                wv[j] = ww;
                amv[c][j] += ww;
            }
            s16x8 af;
            u32* afp = (u32*)&af;
#pragma unroll
            for (int j = 0; j < 4; j++) afp[j] = pk_bf16(wv[2 * j], wv[2 * j + 1]);
            __builtin_amdgcn_s_setprio(1);  // R7: favor this wave's MFMA burst
#pragma unroll
            for (int ft = 0; ft < 4; ft++)
                acc[ft] = __builtin_amdgcn_mfma_f32_16x16x32_bf16(af, Bc[ft], acc[ft], 0, 0, 0);
            __builtin_amdgcn_s_setprio(0);
#pragma unroll
            for (int ft = 0; ft < 4; ft++) Bc[ft] = Bn[ft];
        }
    }
    // ---- deferred att_mean stores (after all loads/MFMA; nothing waits on these)
    if (isbf) {
#pragma unroll
        for (int c = 0; c < 4; c++) {
            s16x8 amp;
            u32* ampp = (u32*)&amp;
#pragma unroll
            for (int j = 0; j < 4; j++) ampp[j] = pk_bf16(amv[c][2 * j], amv[c][2 * j + 1]);
            *(s16x8*)(amb + am_base + c * 32) = amp;
        }
    } else {
#pragma unroll
        for (int c = 0; c < 4; c++) {
            f32x4 lo, hi;
#pragma unroll
            for (int j = 0; j < 4; j++) { lo[j] = amv[c][j]; hi[j] = amv[c][j + 4]; }
            *(f32x4*)(amf + am_base + c * 32) = lo;
            *(f32x4*)(amf + am_base + c * 32 + 4) = hi;
        }
    }
#pragma unroll
    for (int ft = 0; ft < 4; ft++) {
#pragma unroll
        for (int r = 0; r < 4; r++) {
            int pout = p0 + quad * 4 + r;
            int f = ft * 16 + l15;
            atomicAdd(&partf[(size_t)(b * N_ + pout) * F_ + f], acc[ft][r]);
        }
    }
}

__global__ __launch_bounds__(256) void k3_reduce(const float* __restrict__ partf,
                                                 const u32* __restrict__ flag,
                                                 void* __restrict__ out) {
    int idx = blockIdx.x * 256 + threadIdx.x;
    float s = partf[idx];
    if (*flag)
        ((u16*)out)[idx] = f2bf(s);
    else
        ((float*)out)[idx] = s;
}

extern "C" void kernel_launch(void* const* d_in, const int* in_sizes, int n_in,
                              void* d_out, int out_size, void* d_ws, size_t ws_size,
                              hipStream_t stream) {
    const void* h = d_in[0];
    const int* adj = (const int*)d_in[1];
    const void* W = d_in[2];
    const void* a1 = d_in[3];
    const void* a2 = d_in[4];

    char* ws = (char*)d_ws;
    u32* flag = (u32*)(ws + 0);
    u16* a1c = (u16*)(ws + 64);
    u16* a2c = (u16*)(ws + 192);
    u16* wt = (u16*)(ws + 1024);           //  64 KB, ends 66560
    u16* g_f = (u16*)(ws + 66560);         //   4 MB, ends 4260864
    u16* sdb = (u16*)(ws + 4260864);       //  64 KB, ends 4326400
    u32* e2pn = (u32*)(ws + 4326400);      // 128 KB, ends 4457472
    float* ssA = (float*)(ws + 4457472);   // 128 KB, ends 4588544
    float2* ssE = (float2*)(ws + 4588544); // 256 KB, ends 4850688
    float2* E1 = (float2*)(ws + 4850688);  // 256 KB, ends 5112832
    u32* pk = (u32*)(ws + 5112832);        //   2 MB, ends 7209984
    float* partf = (float*)(ws + 7209984); //   2 MB, ends 9307136 (~9.3 MB)

    const int KC_TOT = IN_ * 256 + 2 * F_ + PARTN_;
    kc_convert<<<(KC_TOT + 255) / 256, 256, 0, stream>>>(h, W, a1, a2, flag, wt, a1c, a2c,
                                                         partf);
    k1_proj<<<512, 256, 0, stream>>>(h, flag, wt, a1c, a2c, g_f, sdb, e2pn, ssA, ssE);
    k2a_rowsum<<<2048, 256, 0, stream>>>(adj, sdb, e2pn, ssA, ssE, E1, pk);
    k2b_attn<<<8192, 64, 0, stream>>>(sdb, e2pn, ssA, E1, (const u32*)pk, g_f, flag,
                                      d_out, partf);
    k3_reduce<<<2048, 256, 0, stream>>>(partf, flag, d_out);
}

// Round 14
// 176.829 us; speedup vs baseline: 1.0650x; 1.0339x over previous
//
#include <hip/hip_runtime.h>
#include <stdint.h>

// GAT layer, B=4 N=2048 IN=128 F=64 H=4. adj int32; float tensors are
// bf16 OR fp32 (detected on-device, inline in kc/k1). Pipeline:
//  kc: dtype flag + convert W(+transpose),a1,a2 -> bf16; zero fp32 part accum
//  k1: MFMA g = h@W (h converted inline); store g_f in MFMA-B-FRAGMENT order;
//      sd/ss dots via LDS-redistributed fp32 sums (1 shuffle, not 192)
//  k2a: read adj once (int4 vec), row sums l -> E1, bitpack adj.
//      R13: R10 algebra ported here -- l = sum_q adj*max(se.x*e2p, se.y*e2n)
//      (exp(lrelu(x)) = max(exp x, exp .2x)); sdb loads + compare/select
//      deleted, S[32]->S[16], -20% mem traffic, -25% VALU.
//  k2b: fused softmax-numerators + att_mean + PV. QS=16 q-splits, 8192
//      single-wave blocks. EMPIRICAL LAWS:
//       - resident waves pinned ~6/CU at VGPR<=128, HALVES >128. KEEP <=128.
//       - only serial-path cuts move duration; memory-locality levers are
//         null-to-negative (R6: FETCH halved, time rose).
//       - g_f LAYOUT FRAGILE (R3 -22%); Bc/Bn roll FRAGILE (R5 -11%).
//       - TWO-COUNTER LAW (R11): softmax inputs MUST stay in the lgkm
//         domain (LDS), B-fragments in vmcnt. Mixing them serializes the
//         prefetch queue (in-order vmcnt retirement), 47.6->70.7.
//      R0 FAILED: 4-wave lockstep 57->72. R1 WIN: deferred am stores ->52.9.
//      R2 FAILED: 2 p-tiles VGPR 160 ->63.2. R3/R4 FAILED: g_f relayout
//      ->64.6. R5 FAILED: alt-buffer refill ->58.7. R6 FAILED: XCD swizzle
//      ->60. R7 WIN: setprio ->50.5. R8 AMBIGUOUS (profile artifact).
//      R9 WIN: T14 prologue split + no-barrier ->49.6. R10 WIN:
//      exp(lrelu)=max ->47.6. R11 FAILED: global e2 prefetch ->70.7.
//      R12: revert to R10 CONFIRMED (47.9-49.1, pipeline 182.8 best).
//      R13: k2b byte-identical; only k2a changed (see above).
//  k3: convert part accum -> h_prime

typedef unsigned char u8;
typedef unsigned short u16;
typedef unsigned int u32;
typedef unsigned long long u64;

typedef float f32x4 __attribute__((ext_vector_type(4)));
typedef short s16x8 __attribute__((ext_vector_type(8)));
typedef u32 u32x4 __attribute__((ext_vector_type(4)));

#define B_ 4
#define N_ 2048
#define IN_ 128
#define F_ 64
#define H_ 4
#define QS_ 16
#define PARTN_ (B_ * N_ * F_)

__device__ __forceinline__ float bf2f(u16 b) {
    u32 u = ((u32)b) << 16;
    return __builtin_bit_cast(float, u);
}
__device__ __forceinline__ u16 f2bf(float f) {
    u32 u = __builtin_bit_cast(u32, f);
    u += 0x7FFFu + ((u >> 16) & 1u);  // RNE
    return (u16)(u >> 16);
}
__device__ __forceinline__ u32 pk_bf16(float a, float b) {
#if defined(__has_builtin)
#if __has_builtin(__builtin_amdgcn_cvt_pk_bf16_f32)
    typedef __bf16 bf2_t __attribute__((ext_vector_type(2)));
    bf2_t p = __builtin_amdgcn_cvt_pk_bf16_f32(a, b);
    return __builtin_bit_cast(u32, p);
#else
    return (u32)f2bf(a) | (((u32)f2bf(b)) << 16);
#endif
#else
    return (u32)f2bf(a) | (((u32)f2bf(b)) << 16);
#endif
}

__device__ __forceinline__ u16 conv_elem(const void* p, int i, u32 isbf) {
    if (isbf) return ((const u16*)p)[i];
    return f2bf(((const float*)p)[i]);
}

// ---------------- kc: dtype detect + convert W/a1/a2 + zero part ----------------
__global__ __launch_bounds__(256) void kc_convert(
    const void* __restrict__ h, const void* __restrict__ W, const void* __restrict__ a1,
    const void* __restrict__ a2, u32* __restrict__ flag, u16* __restrict__ wt,
    u16* __restrict__ a1c, u16* __restrict__ a2c, float* __restrict__ partf) {
    __shared__ int cnt[4];
    __shared__ u32 isbf_s;
    int t = threadIdx.x;
    {  // dtype probe on first 256 words of h (identical result per block)
        u32 w = ((const u32*)h)[t];
        int e0 = (int)((w >> 7) & 0xFFu);
        int sane = (e0 >= 100 && e0 <= 145) ? 1 : 0;
#pragma unroll
        for (int m = 1; m < 64; m <<= 1) sane += __shfl_xor(sane, m, 64);
        if ((t & 63) == 0) cnt[t >> 6] = sane;
    }
    __syncthreads();
    if (t == 0) {
        int s = cnt[0] + cnt[1] + cnt[2] + cnt[3];
        isbf_s = (s >= 128) ? 1u : 0u;
        if (blockIdx.x == 0) *flag = isbf_s;
    }
    __syncthreads();
    u32 isbf = isbf_s;

    int j = blockIdx.x * 256 + t;
    if (j < IN_ * 256) {  // W: [128][256] row-major -> wt[c][k]
        int k = j >> 8, c = j & 255;
        wt[c * IN_ + k] = conv_elem(W, j, isbf);
        return;
    }
    j -= IN_ * 256;
    if (j < F_) {
        a1c[j] = conv_elem(a1, j, isbf);
        return;
    }
    j -= F_;
    if (j < F_) {
        a2c[j] = conv_elem(a2, j, isbf);
        return;
    }
    j -= F_;
    if (j < PARTN_) partf[j] = 0.f;
}

// g_f layout (u16), R1 ft-major order (empirically best; see header):
//   ((((b*H+h)*4 + ft)*64 + chunk)*64 + quad*16 + l15)*8 + j
//   holds g[f = ft*16+l15][q = chunk*32 + quad*8 + j]  (exact MFMA B-fragment)
__global__ __launch_bounds__(256) void k1_proj(
    const void* __restrict__ hraw, const u32* __restrict__ flag, const u16* __restrict__ Wt,
    const u16* __restrict__ a1, const u16* __restrict__ a2,
    u16* __restrict__ g_f, u16* __restrict__ sdb, u32* __restrict__ e2pn,
    float* __restrict__ ssA, float2* __restrict__ ssE) {
    int b = blockIdx.x >> 7;
    int n0 = (blockIdx.x & 127) * 16;
    int w = threadIdx.x >> 6;
    int lane = threadIdx.x & 63;
    int quad = lane >> 4, l15 = lane & 15;
    u32 isbf = *flag;

    f32x4 acc[4];
#pragma unroll
    for (int i = 0; i < 4; i++) acc[i] = 0.0f;

    s16x8 A[4];
    if (isbf) {
        const u16* hb = (const u16*)hraw;
#pragma unroll
        for (int kt = 0; kt < 4; kt++)
            A[kt] = *(const s16x8*)(hb + ((size_t)(b * N_ + n0 + l15) * IN_ + kt * 32 + quad * 8));
    } else {
        const float* hf = (const float*)hraw;
#pragma unroll
        for (int kt = 0; kt < 4; kt++) {
            size_t o = (size_t)(b * N_ + n0 + l15) * IN_ + kt * 32 + quad * 8;
            f32x4 lo = *(const f32x4*)(hf + o);
            f32x4 hi = *(const f32x4*)(hf + o + 4);
            u32* ap = (u32*)&A[kt];
            ap[0] = pk_bf16(lo[0], lo[1]);
            ap[1] = pk_bf16(lo[2], lo[3]);
            ap[2] = pk_bf16(hi[0], hi[1]);
            ap[3] = pk_bf16(hi[2], hi[3]);
        }
    }
#pragma unroll
    for (int kt = 0; kt < 4; kt++) {
#pragma unroll
        for (int ft = 0; ft < 4; ft++) {
            int c = w * 64 + ft * 16 + l15;
            const s16x8* bp = (const s16x8*)(Wt + ((size_t)c * IN_ + kt * 32 + quad * 8));
            acc[ft] = __builtin_amdgcn_mfma_f32_16x16x32_bf16(A[kt], *bp, acc[ft], 0, 0, 0);
        }
    }
    __shared__ float ct[4][64][20];  // [wave][f][n]
#pragma unroll
    for (int ft = 0; ft < 4; ft++)
#pragma unroll
        for (int r = 0; r < 4; r++) ct[w][ft * 16 + l15][quad * 4 + r] = acc[ft][r];
    __syncthreads();

    {  // fragment-order store: block covers quads {gq0, gq0+1} of chunk n0>>5
        int chunk = n0 >> 5;
        int gq0 = (n0 >> 3) & 2;
#pragma unroll
        for (int p = 0; p < 2; p++) {
            int ft = p * 2 + (lane >> 5);
            int lq = (lane >> 4) & 1;
            int fl = lane & 15;
            s16x8 tv;
#pragma unroll
            for (int j = 0; j < 8; j++) tv[j] = (short)f2bf(ct[w][ft * 16 + fl][lq * 8 + j]);
            size_t off =
                ((size_t)(((b * H_ + w) * 4 + ft) * 64 + chunk) * 64 + (gq0 + lq) * 16 + fl) * 8;
            *(s16x8*)(g_f + off) = tv;
        }
    }
    // sd/ss dots: lane -> (n = lane&15, vec = (lane>>4)&1, half = lane>>5)
    {
        int dn = lane & 15;
        int dvec = (lane >> 4) & 1;
        int dhalf = lane >> 5;
        const u16* av = dvec ? a2 : a1;
        float x = 0.f;
#pragma unroll
        for (int i = 0; i < 32; i++) {
            int f = dhalf * 32 + i;
            x += ct[w][f][dn] * bf2f(av[f]);
        }
        x += __shfl_xor(x, 32, 64);
        if (lane < 32) {
            size_t o = (size_t)(b * H_ + w) * N_ + n0 + dn;
            if (dvec == 0) {
                sdb[o] = f2bf(x);
                float e2p = __expf(x), e2n = __expf(0.2f * x);
                e2pn[o] = (((u32)f2bf(e2p)) << 16) | (u32)f2bf(e2n);
            } else {
                ssA[o] = x;
                ssE[o] = make_float2(__expf(x), __expf(0.2f * x));
            }
        }
    }
}

// ---------------- k2a: denominators + adj bitpack ----------------
// R13: l = sum_q adj * max(se.x*e2p[q], se.y*e2n[q])  (R10 algebra).
// No sdb loads, no tau, no compare; S[16] accumulators (was 32).
__global__ __launch_bounds__(256) void k2a_rowsum(
    const int* __restrict__ adj, const u16* __restrict__ sdb, const u32* __restrict__ e2pn,
    const float* __restrict__ ssA, const float2* __restrict__ ssE,
    float2* __restrict__ E1, u32* __restrict__ pk32) {
    int b = blockIdx.x >> 9;
    int p0 = (blockIdx.x & 511) * 4;
    int t = threadIdx.x;
    int w = t >> 6, lane = t & 63;

    __shared__ u8 nib[4][512];

    float sex[4][4], sey[4][4];  // se = (exp(ssA), exp(0.2 ssA)) per (r,hh)
#pragma unroll
    for (int r = 0; r < 4; r++)
#pragma unroll
        for (int hh = 0; hh < 4; hh++) {
            float2 se = ssE[(size_t)(b * H_ + hh) * N_ + p0 + r];
            sex[r][hh] = se.x;
            sey[r][hh] = se.y;
        }

    float S[16];  // [r*4+hh]
#pragma unroll
    for (int i = 0; i < 16; i++) S[i] = 0.f;

#pragma unroll
    for (int i = 0; i < 2; i++) {
        int qi = i * 256 + t;
        int q = qi * 4;
        float af[4][4];
#pragma unroll
        for (int r = 0; r < 4; r++) {
            int4 av = *(const int4*)(adj + (size_t)(b * N_ + p0 + r) * N_ + q);
            af[r][0] = (av.x != 0) ? 1.f : 0.f;
            af[r][1] = (av.y != 0) ? 1.f : 0.f;
            af[r][2] = (av.z != 0) ? 1.f : 0.f;
            af[r][3] = (av.w != 0) ? 1.f : 0.f;
            u32 nb = (av.x != 0 ? 1u : 0u) | (av.y != 0 ? 2u : 0u) |
                     (av.z != 0 ? 4u : 0u) | (av.w != 0 ? 8u : 0u);
            nib[r][qi] = (u8)nb;
        }
#pragma unroll
        for (int hh = 0; hh < 4; hh++) {
            size_t o = (size_t)(b * H_ + hh) * N_ + q;
            u32x4 pn4 = *(const u32x4*)(e2pn + o);
            float e2p[4], e2n[4];
#pragma unroll
            for (int j = 0; j < 4; j++) {
                e2p[j] = __builtin_bit_cast(float, pn4[j] & 0xFFFF0000u);
                e2n[j] = __builtin_bit_cast(float, pn4[j] << 16);
            }
#pragma unroll
            for (int r = 0; r < 4; r++) {
#pragma unroll
                for (int j = 0; j < 4; j++) {
                    float m = fmaxf(sex[r][hh] * e2p[j], sey[r][hh] * e2n[j]);
                    S[r * 4 + hh] += af[r][j] * m;
                }
            }
        }
    }
    __syncthreads();
    {
        int r = t >> 6, m8 = t & 63;
        u64 nn = *(const u64*)&nib[r][m8 * 8];
        u32 wd = 0;
#pragma unroll
        for (int d = 0; d < 4; d++) {
            u32 lo = (u32)(nn >> (16 * d)) & 0xFu;
            u32 hi = (u32)(nn >> (16 * d + 8)) & 0xFu;
            wd |= (lo | (hi << 4)) << (8 * d);
        }
        pk32[(size_t)(b * N_ + p0 + r) * 64 + m8] = wd;
    }
#pragma unroll
    for (int k = 0; k < 16; k++) {
        float x = S[k];
#pragma unroll
        for (int m = 1; m < 64; m <<= 1) x += __shfl_xor(x, m, 64);
        S[k] = x;
    }
    __shared__ float sred[4][16];
    if (lane == 0) {
#pragma unroll
        for (int k = 0; k < 16; k++) sred[w][k] = S[k];
    }
    __syncthreads();
    if (t < 16) {
        int r = t >> 2, hh = t & 3;
        float l = 0.f;
#pragma unroll
        for (int ww = 0; ww < 4; ww++) l += sred[ww][t];
        size_t o = (size_t)(b * H_ + hh) * N_ + p0 + r;
        float2 se = ssE[o];
        float inv = (l > 0.f) ? 0.25f / l : 0.f;  // fold 1/H and 1/l
        E1[o] = make_float2(se.x * inv, se.y * inv);
    }
}

// ---------------- k2b: fused attention + att_mean + PV ----------------
// grid = B * 128 ptiles * 16 qsplits = 8192 single-wave blocks (128 q each).
// BYTE-IDENTICAL to R12 (verified 47.9-49.1us, VGPR 104, LDS 2048).
// R10: w = bit * max(E1p*exp(sd), E1n*exp(0.2 sd)).
// R9: T14 prologue split, no __syncthreads (single-wave block).
// R7: setprio around MFMA cluster. R1: am accumulated in regs, stored once
// at the end. TWO-COUNTER LAW (R11): le2 stays in LDS/lgkm; B-fragments in
// vmcnt -- the two wait queues pipeline against each other.
__global__ __launch_bounds__(64) void k2b_attn(
    const u16* __restrict__ sdb, const u32* __restrict__ e2pn, const float* __restrict__ ssA,
    const float2* __restrict__ E1, const u32* __restrict__ pk32,
    const u16* __restrict__ g_f, const u32* __restrict__ flag, void* __restrict__ d_out_v,
    float* __restrict__ partf) {
    int bid = blockIdx.x;
    int s = bid & (QS_ - 1);
    int pt = (bid >> 4) & 127;
    int b = bid >> 11;
    int qb = s * (N_ / QS_);  // 128 q per block
    int lane = threadIdx.x;   // 0..63
    int quad = lane >> 4, l15 = lane & 15;
    int p0 = pt * 16;
    int row = p0 + l15;
    u32 isbf = *flag;

    __shared__ __align__(8) u32 le2[4][128];

    // ---- T14 issue-early: staging loads first (oldest -> retire first)
    u64 t_e2[4];
#pragma unroll
    for (int hh = 0; hh < 4; hh++) {
        size_t o = (size_t)(b * H_ + hh) * N_ + qb + lane * 2;
        t_e2[hh] = *(const u64*)(e2pn + o);
    }

    // ---- newer loads issued while staging loads are in flight
    float E1p[4], E1n[4];
#pragma unroll
    for (int hh = 0; hh < 4; hh++) {
        size_t o = (size_t)(b * H_ + hh) * N_ + row;
        float2 e1 = E1[o];
        E1p[hh] = e1.x;
        E1n[hh] = e1.y;
    }
    const u32* pkrow = pk32 + (size_t)(b * N_ + row) * 64 + (qb >> 5);
    u32 pkw[4];
#pragma unroll
    for (int c = 0; c < 4; c++) pkw[c] = pkrow[c];

    const size_t hstride = (size_t)4 * 64 * 512;  // per-head span in u16
    const u16* gb = g_f + (size_t)b * H_ * hstride + (size_t)(qb >> 5) * 512 + lane * 8;

    s16x8 Bc[4], Bn[4];
#pragma unroll
    for (int ft = 0; ft < 4; ft++) Bc[ft] = *(const s16x8*)(gb + (size_t)ft * 32768);

    // ---- write-late: LDS staging (waits only the oldest loads; Bc stays
    // in flight). Single-wave block: no barrier needed, lgkmcnt orders
    // ds_write -> ds_read.
#pragma unroll
    for (int hh = 0; hh < 4; hh++) {
        *(u64*)&le2[hh][lane * 2] = t_e2[hh];
    }

    f32x4 acc[4];  // shared across heads (h' sums over heads)
#pragma unroll
    for (int i = 0; i < 4; i++) acc[i] = 0.0f;

    size_t am_base = ((size_t)(b * N_ + row)) * N_ + qb + quad * 8;
    u16* amb = (u16*)d_out_v + (size_t)B_ * N_ * F_;
    float* amf = (float*)d_out_v + (size_t)B_ * N_ * F_;

    float amv[4][8];  // att_mean accum, per c; static indices only (full unroll)
#pragma unroll
    for (int c = 0; c < 4; c++)
#pragma unroll
        for (int j = 0; j < 8; j++) amv[c][j] = 0.f;

#pragma unroll
    for (int c = 0; c < 4; c++) {
        int qq = c * 32 + quad * 8;
        u32 byte_ = (pkw[c] >> (quad * 8)) & 0xFFu;

#pragma unroll
        for (int hh = 0; hh < 4; hh++) {
            {  // prefetch next (c,hh) stage's B fragments
                int idx = (c * 4 + hh + 1) & 15;
                int c2 = idx >> 2, h2 = idx & 3;
#pragma unroll
                for (int ft = 0; ft < 4; ft++)
                    Bn[ft] = *(const s16x8*)(gb + (size_t)h2 * hstride + (size_t)ft * 32768 +
                                             (size_t)c2 * 512);
            }
            u32x4 e2a = *(const u32x4*)&le2[hh][qq];
            u32x4 e2b = *(const u32x4*)&le2[hh][qq + 4];
            float wv[8];
#pragma unroll
            for (int j = 0; j < 8; j++) {
                u32 pn = (j < 4) ? e2a[j] : e2b[j - 4];
                float ep = __builtin_bit_cast(float, pn & 0xFFFF0000u);
                float en = __builtin_bit_cast(float, pn << 16);
                float ww = fmaxf(E1p[hh] * ep, E1n[hh] * en);
                ww = ((byte_ >> j) & 1u) ? ww : 0.f;
                wv[j] = ww;
                amv[c][j] += ww;
            }
            s16x8 af;
            u32* afp = (u32*)&af;
#pragma unroll
            for (int j = 0; j < 4; j++) afp[j] = pk_bf16(wv[2 * j], wv[2 * j + 1]);
            __builtin_amdgcn_s_setprio(1);  // R7: favor this wave's MFMA burst
#pragma unroll
            for (int ft = 0; ft < 4; ft++)
                acc[ft] = __builtin_amdgcn_mfma_f32_16x16x32_bf16(af, Bc[ft], acc[ft], 0, 0, 0);
            __builtin_amdgcn_s_setprio(0);
#pragma unroll
            for (int ft = 0; ft < 4; ft++) Bc[ft] = Bn[ft];
        }
    }
    // ---- deferred att_mean stores (after all loads/MFMA; nothing waits on these)
    if (isbf) {
#pragma unroll
        for (int c = 0; c < 4; c++) {
            s16x8 amp;
            u32* ampp = (u32*)&amp;
#pragma unroll
            for (int j = 0; j < 4; j++) ampp[j] = pk_bf16(amv[c][2 * j], amv[c][2 * j + 1]);
            *(s16x8*)(amb + am_base + c * 32) = amp;
        }
    } else {
#pragma unroll
        for (int c = 0; c < 4; c++) {
            f32x4 lo, hi;
#pragma unroll
            for (int j = 0; j < 4; j++) { lo[j] = amv[c][j]; hi[j] = amv[c][j + 4]; }
            *(f32x4*)(amf + am_base + c * 32) = lo;
            *(f32x4*)(amf + am_base + c * 32 + 4) = hi;
        }
    }
#pragma unroll
    for (int ft = 0; ft < 4; ft++) {
#pragma unroll
        for (int r = 0; r < 4; r++) {
            int pout = p0 + quad * 4 + r;
            int f = ft * 16 + l15;
            atomicAdd(&partf[(size_t)(b * N_ + pout) * F_ + f], acc[ft][r]);
        }
    }
}

__global__ __launch_bounds__(256) void k3_reduce(const float* __restrict__ partf,
                                                 const u32* __restrict__ flag,
                                                 void* __restrict__ out) {
    int idx = blockIdx.x * 256 + threadIdx.x;
    float s = partf[idx];
    if (*flag)
        ((u16*)out)[idx] = f2bf(s);
    else
        ((float*)out)[idx] = s;
}

extern "C" void kernel_launch(void* const* d_in, const int* in_sizes, int n_in,
                              void* d_out, int out_size, void* d_ws, size_t ws_size,
                              hipStream_t stream) {
    const void* h = d_in[0];
    const int* adj = (const int*)d_in[1];
    const void* W = d_in[2];
    const void* a1 = d_in[3];
    const void* a2 = d_in[4];

    char* ws = (char*)d_ws;
    u32* flag = (u32*)(ws + 0);
    u16* a1c = (u16*)(ws + 64);
    u16* a2c = (u16*)(ws + 192);
    u16* wt = (u16*)(ws + 1024);           //  64 KB, ends 66560
    u16* g_f = (u16*)(ws + 66560);         //   4 MB, ends 4260864
    u16* sdb = (u16*)(ws + 4260864);       //  64 KB, ends 4326400
    u32* e2pn = (u32*)(ws + 4326400);      // 128 KB, ends 4457472
    float* ssA = (float*)(ws + 4457472);   // 128 KB, ends 4588544
    float2* ssE = (float2*)(ws + 4588544); // 256 KB, ends 4850688
    float2* E1 = (float2*)(ws + 4850688);  // 256 KB, ends 5112832
    u32* pk = (u32*)(ws + 5112832);        //   2 MB, ends 7209984
    float* partf = (float*)(ws + 7209984); //   2 MB, ends 9307136 (~9.3 MB)

    const int KC_TOT = IN_ * 256 + 2 * F_ + PARTN_;
    kc_convert<<<(KC_TOT + 255) / 256, 256, 0, stream>>>(h, W, a1, a2, flag, wt, a1c, a2c,
                                                         partf);
    k1_proj<<<512, 256, 0, stream>>>(h, flag, wt, a1c, a2c, g_f, sdb, e2pn, ssA, ssE);
    k2a_rowsum<<<2048, 256, 0, stream>>>(adj, sdb, e2pn, ssA, ssE, E1, pk);
    k2b_attn<<<8192, 64, 0, stream>>>(sdb, e2pn, ssA, E1, (const u32*)pk, g_f, flag,
                                      d_out, partf);
    k3_reduce<<<2048, 256, 0, stream>>>(partf, flag, d_out);
}

// Round 15
// 175.452 us; speedup vs baseline: 1.0734x; 1.0078x over previous
//
#include <hip/hip_runtime.h>
#include <stdint.h>

// GAT layer, B=4 N=2048 IN=128 F=64 H=4. adj int32; float tensors are
// bf16 OR fp32 (detected on-device, inline in kc/k1). Pipeline:
//  kc: dtype flag + convert W(+transpose),a1,a2 -> bf16; zero fp32 part accum
//  k1: MFMA g = h@W (h converted inline); store g_f in MFMA-B-FRAGMENT order;
//      sd/ss dots via LDS-redistributed fp32 sums (1 shuffle, not 192)
//  k2a: read adj once (int4 vec), row sums l -> E1, bitpack adj.
//      R13: l = sex * sum_q adj*max(e2p, ratio*e2n) (exp(lrelu)=max identity)
//      R14: ratio = sey/sex hoisted per (r,hh) -> inner loop 4->3 VALU.
//  k2b: fused softmax-numerators + att_mean + PV. R14: QS=8 q-splits, 4096
//      single-wave blocks (256 q / 32 stages per wave) -- halves per-work
//      prologue/epilogue cost and partf atomic traffic; one mid-loop am
//      flush at c==4 (R1 cost at exactly one point). EMPIRICAL LAWS:
//       - resident waves pinned ~6/CU at VGPR<=128, HALVES >128. KEEP <=128.
//       - only serial-path cuts move duration; memory-locality levers are
//         null-to-negative (R6: FETCH halved, time rose).
//       - g_f LAYOUT FRAGILE (R3 -22%); Bc/Bn roll FRAGILE (R5 -11%).
//       - TWO-COUNTER LAW (R11): softmax inputs stay in lgkm (LDS);
//         B-fragments in vmcnt. Mixing serializes the prefetch queue.
//      R0 FAILED lockstep. R1 WIN deferred am stores ->52.9. R2 FAILED
//      2-ptile VGPR. R3/R4 FAILED relayout. R5 FAILED alt-buffer.
//      R6 FAILED XCD swizzle. R7 WIN setprio ->50.5. R8 QS=8 graded tie
//      (profile artifact). R9 WIN prologue split ->49.6. R10 WIN
//      exp(lrelu)=max ->47.6. R11 FAILED global e2 ->70.7. R12 revert
//      CONFIRMED. R13 WIN k2a algebra, pipeline 182.8->176.8.
//  k3: convert part accum -> h_prime

typedef unsigned char u8;
typedef unsigned short u16;
typedef unsigned int u32;
typedef unsigned long long u64;

typedef float f32x4 __attribute__((ext_vector_type(4)));
typedef short s16x8 __attribute__((ext_vector_type(8)));
typedef u32 u32x4 __attribute__((ext_vector_type(4)));

#define B_ 4
#define N_ 2048
#define IN_ 128
#define F_ 64
#define H_ 4
#define QS2B_ 8
#define PARTN_ (B_ * N_ * F_)

__device__ __forceinline__ float bf2f(u16 b) {
    u32 u = ((u32)b) << 16;
    return __builtin_bit_cast(float, u);
}
__device__ __forceinline__ u16 f2bf(float f) {
    u32 u = __builtin_bit_cast(u32, f);
    u += 0x7FFFu + ((u >> 16) & 1u);  // RNE
    return (u16)(u >> 16);
}
__device__ __forceinline__ u32 pk_bf16(float a, float b) {
#if defined(__has_builtin)
#if __has_builtin(__builtin_amdgcn_cvt_pk_bf16_f32)
    typedef __bf16 bf2_t __attribute__((ext_vector_type(2)));
    bf2_t p = __builtin_amdgcn_cvt_pk_bf16_f32(a, b);
    return __builtin_bit_cast(u32, p);
#else
    return (u32)f2bf(a) | (((u32)f2bf(b)) << 16);
#endif
#else
    return (u32)f2bf(a) | (((u32)f2bf(b)) << 16);
#endif
}

__device__ __forceinline__ u16 conv_elem(const void* p, int i, u32 isbf) {
    if (isbf) return ((const u16*)p)[i];
    return f2bf(((const float*)p)[i]);
}

// ---------------- kc: dtype detect + convert W/a1/a2 + zero part ----------------
__global__ __launch_bounds__(256) void kc_convert(
    const void* __restrict__ h, const void* __restrict__ W, const void* __restrict__ a1,
    const void* __restrict__ a2, u32* __restrict__ flag, u16* __restrict__ wt,
    u16* __restrict__ a1c, u16* __restrict__ a2c, float* __restrict__ partf) {
    __shared__ int cnt[4];
    __shared__ u32 isbf_s;
    int t = threadIdx.x;
    {  // dtype probe on first 256 words of h (identical result per block)
        u32 w = ((const u32*)h)[t];
        int e0 = (int)((w >> 7) & 0xFFu);
        int sane = (e0 >= 100 && e0 <= 145) ? 1 : 0;
#pragma unroll
        for (int m = 1; m < 64; m <<= 1) sane += __shfl_xor(sane, m, 64);
        if ((t & 63) == 0) cnt[t >> 6] = sane;
    }
    __syncthreads();
    if (t == 0) {
        int s = cnt[0] + cnt[1] + cnt[2] + cnt[3];
        isbf_s = (s >= 128) ? 1u : 0u;
        if (blockIdx.x == 0) *flag = isbf_s;
    }
    __syncthreads();
    u32 isbf = isbf_s;

    int j = blockIdx.x * 256 + t;
    if (j < IN_ * 256) {  // W: [128][256] row-major -> wt[c][k]
        int k = j >> 8, c = j & 255;
        wt[c * IN_ + k] = conv_elem(W, j, isbf);
        return;
    }
    j -= IN_ * 256;
    if (j < F_) {
        a1c[j] = conv_elem(a1, j, isbf);
        return;
    }
    j -= F_;
    if (j < F_) {
        a2c[j] = conv_elem(a2, j, isbf);
        return;
    }
    j -= F_;
    if (j < PARTN_) partf[j] = 0.f;
}

// g_f layout (u16), R1 ft-major order (empirically best; see header):
//   ((((b*H+h)*4 + ft)*64 + chunk)*64 + quad*16 + l15)*8 + j
//   holds g[f = ft*16+l15][q = chunk*32 + quad*8 + j]  (exact MFMA B-fragment)
__global__ __launch_bounds__(256) void k1_proj(
    const void* __restrict__ hraw, const u32* __restrict__ flag, const u16* __restrict__ Wt,
    const u16* __restrict__ a1, const u16* __restrict__ a2,
    u16* __restrict__ g_f, u16* __restrict__ sdb, u32* __restrict__ e2pn,
    float* __restrict__ ssA, float2* __restrict__ ssE) {
    int b = blockIdx.x >> 7;
    int n0 = (blockIdx.x & 127) * 16;
    int w = threadIdx.x >> 6;
    int lane = threadIdx.x & 63;
    int quad = lane >> 4, l15 = lane & 15;
    u32 isbf = *flag;

    f32x4 acc[4];
#pragma unroll
    for (int i = 0; i < 4; i++) acc[i] = 0.0f;

    s16x8 A[4];
    if (isbf) {
        const u16* hb = (const u16*)hraw;
#pragma unroll
        for (int kt = 0; kt < 4; kt++)
            A[kt] = *(const s16x8*)(hb + ((size_t)(b * N_ + n0 + l15) * IN_ + kt * 32 + quad * 8));
    } else {
        const float* hf = (const float*)hraw;
#pragma unroll
        for (int kt = 0; kt < 4; kt++) {
            size_t o = (size_t)(b * N_ + n0 + l15) * IN_ + kt * 32 + quad * 8;
            f32x4 lo = *(const f32x4*)(hf + o);
            f32x4 hi = *(const f32x4*)(hf + o + 4);
            u32* ap = (u32*)&A[kt];
            ap[0] = pk_bf16(lo[0], lo[1]);
            ap[1] = pk_bf16(lo[2], lo[3]);
            ap[2] = pk_bf16(hi[0], hi[1]);
            ap[3] = pk_bf16(hi[2], hi[3]);
        }
    }
#pragma unroll
    for (int kt = 0; kt < 4; kt++) {
#pragma unroll
        for (int ft = 0; ft < 4; ft++) {
            int c = w * 64 + ft * 16 + l15;
            const s16x8* bp = (const s16x8*)(Wt + ((size_t)c * IN_ + kt * 32 + quad * 8));
            acc[ft] = __builtin_amdgcn_mfma_f32_16x16x32_bf16(A[kt], *bp, acc[ft], 0, 0, 0);
        }
    }
    __shared__ float ct[4][64][20];  // [wave][f][n]
#pragma unroll
    for (int ft = 0; ft < 4; ft++)
#pragma unroll
        for (int r = 0; r < 4; r++) ct[w][ft * 16 + l15][quad * 4 + r] = acc[ft][r];
    __syncthreads();

    {  // fragment-order store: block covers quads {gq0, gq0+1} of chunk n0>>5
        int chunk = n0 >> 5;
        int gq0 = (n0 >> 3) & 2;
#pragma unroll
        for (int p = 0; p < 2; p++) {
            int ft = p * 2 + (lane >> 5);
            int lq = (lane >> 4) & 1;
            int fl = lane & 15;
            s16x8 tv;
#pragma unroll
            for (int j = 0; j < 8; j++) tv[j] = (short)f2bf(ct[w][ft * 16 + fl][lq * 8 + j]);
            size_t off =
                ((size_t)(((b * H_ + w) * 4 + ft) * 64 + chunk) * 64 + (gq0 + lq) * 16 + fl) * 8;
            *(s16x8*)(g_f + off) = tv;
        }
    }
    // sd/ss dots: lane -> (n = lane&15, vec = (lane>>4)&1, half = lane>>5)
    {
        int dn = lane & 15;
        int dvec = (lane >> 4) & 1;
        int dhalf = lane >> 5;
        const u16* av = dvec ? a2 : a1;
        float x = 0.f;
#pragma unroll
        for (int i = 0; i < 32; i++) {
            int f = dhalf * 32 + i;
            x += ct[w][f][dn] * bf2f(av[f]);
        }
        x += __shfl_xor(x, 32, 64);
        if (lane < 32) {
            size_t o = (size_t)(b * H_ + w) * N_ + n0 + dn;
            if (dvec == 0) {
                sdb[o] = f2bf(x);
                float e2p = __expf(x), e2n = __expf(0.2f * x);
                e2pn[o] = (((u32)f2bf(e2p)) << 16) | (u32)f2bf(e2n);
            } else {
                ssA[o] = x;
                ssE[o] = make_float2(__expf(x), __expf(0.2f * x));
            }
        }
    }
}

// ---------------- k2a: denominators + adj bitpack ----------------
// R13/R14: l = sex * sum_q adj * max(e2p[q], ratio*e2n[q]), ratio=sey/sex
// hoisted per (r,hh). No sdb loads, no compare; S[16]; 3-op inner.
__global__ __launch_bounds__(256) void k2a_rowsum(
    const int* __restrict__ adj, const u16* __restrict__ sdb, const u32* __restrict__ e2pn,
    const float* __restrict__ ssA, const float2* __restrict__ ssE,
    float2* __restrict__ E1, u32* __restrict__ pk32) {
    int b = blockIdx.x >> 9;
    int p0 = (blockIdx.x & 511) * 4;
    int t = threadIdx.x;
    int w = t >> 6, lane = t & 63;

    __shared__ u8 nib[4][512];

    float ratio[4][4];  // sey/sex per (r,hh); exact div, 16/block
#pragma unroll
    for (int r = 0; r < 4; r++)
#pragma unroll
        for (int hh = 0; hh < 4; hh++) {
            float2 se = ssE[(size_t)(b * H_ + hh) * N_ + p0 + r];
            ratio[r][hh] = se.y / se.x;
        }

    float S[16];  // [r*4+hh], scaled by 1/sex (applied in tail)
#pragma unroll
    for (int i = 0; i < 16; i++) S[i] = 0.f;

#pragma unroll
    for (int i = 0; i < 2; i++) {
        int qi = i * 256 + t;
        int q = qi * 4;
        float af[4][4];
#pragma unroll
        for (int r = 0; r < 4; r++) {
            int4 av = *(const int4*)(adj + (size_t)(b * N_ + p0 + r) * N_ + q);
            af[r][0] = (av.x != 0) ? 1.f : 0.f;
            af[r][1] = (av.y != 0) ? 1.f : 0.f;
            af[r][2] = (av.z != 0) ? 1.f : 0.f;
            af[r][3] = (av.w != 0) ? 1.f : 0.f;
            u32 nb = (av.x != 0 ? 1u : 0u) | (av.y != 0 ? 2u : 0u) |
                     (av.z != 0 ? 4u : 0u) | (av.w != 0 ? 8u : 0u);
            nib[r][qi] = (u8)nb;
        }
#pragma unroll
        for (int hh = 0; hh < 4; hh++) {
            size_t o = (size_t)(b * H_ + hh) * N_ + q;
            u32x4 pn4 = *(const u32x4*)(e2pn + o);
            float e2p[4], e2n[4];
#pragma unroll
            for (int j = 0; j < 4; j++) {
                e2p[j] = __builtin_bit_cast(float, pn4[j] & 0xFFFF0000u);
                e2n[j] = __builtin_bit_cast(float, pn4[j] << 16);
            }
#pragma unroll
            for (int r = 0; r < 4; r++) {
#pragma unroll
                for (int j = 0; j < 4; j++) {
                    float m = fmaxf(e2p[j], ratio[r][hh] * e2n[j]);
                    S[r * 4 + hh] += af[r][j] * m;
                }
            }
        }
    }
    __syncthreads();
    {
        int r = t >> 6, m8 = t & 63;
        u64 nn = *(const u64*)&nib[r][m8 * 8];
        u32 wd = 0;
#pragma unroll
        for (int d = 0; d < 4; d++) {
            u32 lo = (u32)(nn >> (16 * d)) & 0xFu;
            u32 hi = (u32)(nn >> (16 * d + 8)) & 0xFu;
            wd |= (lo | (hi << 4)) << (8 * d);
        }
        pk32[(size_t)(b * N_ + p0 + r) * 64 + m8] = wd;
    }
#pragma unroll
    for (int k = 0; k < 16; k++) {
        float x = S[k];
#pragma unroll
        for (int m = 1; m < 64; m <<= 1) x += __shfl_xor(x, m, 64);
        S[k] = x;
    }
    __shared__ float sred[4][16];
    if (lane == 0) {
#pragma unroll
        for (int k = 0; k < 16; k++) sred[w][k] = S[k];
    }
    __syncthreads();
    if (t < 16) {
        int r = t >> 2, hh = t & 3;
        float sp = 0.f;
#pragma unroll
        for (int ww = 0; ww < 4; ww++) sp += sred[ww][t];
        size_t o = (size_t)(b * H_ + hh) * N_ + p0 + r;
        float2 se = ssE[o];
        float l = se.x * sp;  // undo the 1/sex factoring
        float inv = (l > 0.f) ? 0.25f / l : 0.f;  // fold 1/H and 1/l
        E1[o] = make_float2(se.x * inv, se.y * inv);
    }
}

// ---------------- k2b: fused attention + att_mean + PV ----------------
// grid = B * 128 ptiles * 8 qsplits = 4096 single-wave blocks (256 q each).
// R14: 32 stages/wave (c=0..7 x hh); amv[4][8] reused across halves with
// ONE mid-loop am flush at c==4. Stage body byte-equivalent to R12
// (verified 47.5-48us). R10: w = bit*max(E1p*ep, E1n*en). R9: T14 prologue
// split, no __syncthreads (single-wave block). R7: setprio around MFMA
// cluster. R1: am stores kept off the load path. TWO-COUNTER LAW (R11):
// le2 in LDS/lgkm; B-fragments in vmcnt.
__global__ __launch_bounds__(64) void k2b_attn(
    const u16* __restrict__ sdb, const u32* __restrict__ e2pn, const float* __restrict__ ssA,
    const float2* __restrict__ E1, const u32* __restrict__ pk32,
    const u16* __restrict__ g_f, const u32* __restrict__ flag, void* __restrict__ d_out_v,
    float* __restrict__ partf) {
    int bid = blockIdx.x;
    int s = bid & (QS2B_ - 1);
    int pt = (bid >> 3) & 127;
    int b = bid >> 10;
    int qb = s * (N_ / QS2B_);  // 256 q per block
    int lane = threadIdx.x;     // 0..63
    int quad = lane >> 4, l15 = lane & 15;
    int p0 = pt * 16;
    int row = p0 + l15;
    u32 isbf = *flag;

    __shared__ __align__(16) u32 le2[4][256];

    // ---- T14 issue-early: staging loads first (oldest -> retire first)
    u32x4 t_e2[4];
#pragma unroll
    for (int hh = 0; hh < 4; hh++) {
        size_t o = (size_t)(b * H_ + hh) * N_ + qb + lane * 4;
        t_e2[hh] = *(const u32x4*)(e2pn + o);
    }

    // ---- newer loads issued while staging loads are in flight
    float E1p[4], E1n[4];
#pragma unroll
    for (int hh = 0; hh < 4; hh++) {
        size_t o = (size_t)(b * H_ + hh) * N_ + row;
        float2 e1 = E1[o];
        E1p[hh] = e1.x;
        E1n[hh] = e1.y;
    }
    const u32* pkrow = pk32 + (size_t)(b * N_ + row) * 64 + (qb >> 5);
    u32 pkw[8];
    *(u32x4*)&pkw[0] = *(const u32x4*)pkrow;
    *(u32x4*)&pkw[4] = *(const u32x4*)(pkrow + 4);

    const size_t hstride = (size_t)4 * 64 * 512;  // per-head span in u16
    const u16* gb = g_f + (size_t)b * H_ * hstride + (size_t)(qb >> 5) * 512 + lane * 8;

    s16x8 Bc[4], Bn[4];
#pragma unroll
    for (int ft = 0; ft < 4; ft++) Bc[ft] = *(const s16x8*)(gb + (size_t)ft * 32768);

    // ---- write-late: LDS staging (waits only the oldest loads; Bc stays
    // in flight). Single-wave block: no barrier needed, lgkmcnt orders
    // ds_write -> ds_read.
#pragma unroll
    for (int hh = 0; hh < 4; hh++) {
        *(u32x4*)&le2[hh][lane * 4] = t_e2[hh];
    }

    f32x4 acc[4];  // shared across heads (h' sums over heads)
#pragma unroll
    for (int i = 0; i < 4; i++) acc[i] = 0.0f;

    size_t am_base = ((size_t)(b * N_ + row)) * N_ + qb + quad * 8;
    u16* amb = (u16*)d_out_v + (size_t)B_ * N_ * F_;
    float* amf = (float*)d_out_v + (size_t)B_ * N_ * F_;

    float amv[4][8];  // att_mean accum for current 4-c half; static idx only
#pragma unroll
    for (int c = 0; c < 4; c++)
#pragma unroll
        for (int j = 0; j < 8; j++) amv[c][j] = 0.f;

#pragma unroll
    for (int c = 0; c < 8; c++) {
        if (c == 4) {  // mid-loop flush of am for c=0..3; reuse amv regs
            if (isbf) {
#pragma unroll
                for (int k = 0; k < 4; k++) {
                    s16x8 amp;
                    u32* ampp = (u32*)&amp;
#pragma unroll
                    for (int j = 0; j < 4; j++)
                        ampp[j] = pk_bf16(amv[k][2 * j], amv[k][2 * j + 1]);
                    *(s16x8*)(amb + am_base + k * 32) = amp;
                }
            } else {
#pragma unroll
                for (int k = 0; k < 4; k++) {
                    f32x4 lo, hi;
#pragma unroll
                    for (int j = 0; j < 4; j++) { lo[j] = amv[k][j]; hi[j] = amv[k][j + 4]; }
                    *(f32x4*)(amf + am_base + k * 32) = lo;
                    *(f32x4*)(amf + am_base + k * 32 + 4) = hi;
                }
            }
#pragma unroll
            for (int k = 0; k < 4; k++)
#pragma unroll
                for (int j = 0; j < 8; j++) amv[k][j] = 0.f;
        }
        int qq = c * 32 + quad * 8;
        u32 byte_ = (pkw[c] >> (quad * 8)) & 0xFFu;

#pragma unroll
        for (int hh = 0; hh < 4; hh++) {
            {  // prefetch next (c,hh) stage's B fragments
                int idx = (c * 4 + hh + 1) & 31;
                int c2 = idx >> 2, h2 = idx & 3;
#pragma unroll
                for (int ft = 0; ft < 4; ft++)
                    Bn[ft] = *(const s16x8*)(gb + (size_t)h2 * hstride + (size_t)ft * 32768 +
                                             (size_t)c2 * 512);
            }
            u32x4 e2a = *(const u32x4*)&le2[hh][qq];
            u32x4 e2b = *(const u32x4*)&le2[hh][qq + 4];
            float wv[8];
#pragma unroll
            for (int j = 0; j < 8; j++) {
                u32 pn = (j < 4) ? e2a[j] : e2b[j - 4];
                float ep = __builtin_bit_cast(float, pn & 0xFFFF0000u);
                float en = __builtin_bit_cast(float, pn << 16);
                float ww = fmaxf(E1p[hh] * ep, E1n[hh] * en);
                ww = ((byte_ >> j) & 1u) ? ww : 0.f;
                wv[j] = ww;
                amv[c & 3][j] += ww;
            }
            s16x8 af;
            u32* afp = (u32*)&af;
#pragma unroll
            for (int j = 0; j < 4; j++) afp[j] = pk_bf16(wv[2 * j], wv[2 * j + 1]);
            __builtin_amdgcn_s_setprio(1);  // R7: favor this wave's MFMA burst
#pragma unroll
            for (int ft = 0; ft < 4; ft++)
                acc[ft] = __builtin_amdgcn_mfma_f32_16x16x32_bf16(af, Bc[ft], acc[ft], 0, 0, 0);
            __builtin_amdgcn_s_setprio(0);
#pragma unroll
            for (int ft = 0; ft < 4; ft++) Bc[ft] = Bn[ft];
        }
    }
    // ---- final am flush for c=4..7 (after all loads/MFMA)
    if (isbf) {
#pragma unroll
        for (int k = 0; k < 4; k++) {
            s16x8 amp;
            u32* ampp = (u32*)&amp;
#pragma unroll
            for (int j = 0; j < 4; j++) ampp[j] = pk_bf16(amv[k][2 * j], amv[k][2 * j + 1]);
            *(s16x8*)(amb + am_base + (4 + k) * 32) = amp;
        }
    } else {
#pragma unroll
        for (int k = 0; k < 4; k++) {
            f32x4 lo, hi;
#pragma unroll
            for (int j = 0; j < 4; j++) { lo[j] = amv[k][j]; hi[j] = amv[k][j + 4]; }
            *(f32x4*)(amf + am_base + (4 + k) * 32) = lo;
            *(f32x4*)(amf + am_base + (4 + k) * 32 + 4) = hi;
        }
    }
#pragma unroll
    for (int ft = 0; ft < 4; ft++) {
#pragma unroll
        for (int r = 0; r < 4; r++) {
            int pout = p0 + quad * 4 + r;
            int f = ft * 16 + l15;
            atomicAdd(&partf[(size_t)(b * N_ + pout) * F_ + f], acc[ft][r]);
        }
    }
}

__global__ __launch_bounds__(256) void k3_reduce(const float* __restrict__ partf,
                                                 const u32* __restrict__ flag,
                                                 void* __restrict__ out) {
    int idx = blockIdx.x * 256 + threadIdx.x;
    float s = partf[idx];
    if (*flag)
        ((u16*)out)[idx] = f2bf(s);
    else
        ((float*)out)[idx] = s;
}

extern "C" void kernel_launch(void* const* d_in, const int* in_sizes, int n_in,
                              void* d_out, int out_size, void* d_ws, size_t ws_size,
                              hipStream_t stream) {
    const void* h = d_in[0];
    const int* adj = (const int*)d_in[1];
    const void* W = d_in[2];
    const void* a1 = d_in[3];
    const void* a2 = d_in[4];

    char* ws = (char*)d_ws;
    u32* flag = (u32*)(ws + 0);
    u16* a1c = (u16*)(ws + 64);
    u16* a2c = (u16*)(ws + 192);
    u16* wt = (u16*)(ws + 1024);           //  64 KB, ends 66560
    u16* g_f = (u16*)(ws + 66560);         //   4 MB, ends 4260864
    u16* sdb = (u16*)(ws + 4260864);       //  64 KB, ends 4326400
    u32* e2pn = (u32*)(ws + 4326400);      // 128 KB, ends 4457472
    float* ssA = (float*)(ws + 4457472);   // 128 KB, ends 4588544
    float2* ssE = (float2*)(ws + 4588544); // 256 KB, ends 4850688
    float2* E1 = (float2*)(ws + 4850688);  // 256 KB, ends 5112832
    u32* pk = (u32*)(ws + 5112832);        //   2 MB, ends 7209984
    float* partf = (float*)(ws + 7209984); //   2 MB, ends 9307136 (~9.3 MB)

    const int KC_TOT = IN_ * 256 + 2 * F_ + PARTN_;
    kc_convert<<<(KC_TOT + 255) / 256, 256, 0, stream>>>(h, W, a1, a2, flag, wt, a1c, a2c,
                                                         partf);
    k1_proj<<<512, 256, 0, stream>>>(h, flag, wt, a1c, a2c, g_f, sdb, e2pn, ssA, ssE);
    k2a_rowsum<<<2048, 256, 0, stream>>>(adj, sdb, e2pn, ssA, ssE, E1, pk);
    k2b_attn<<<4096, 64, 0, stream>>>(sdb, e2pn, ssA, E1, (const u32*)pk, g_f, flag,
                                      d_out, partf);
    k3_reduce<<<2048, 256, 0, stream>>>(partf, flag, d_out);
}